// Round 1
// baseline (403.585 us; speedup 1.0000x reference)
//
#include <hip/hip_runtime.h>

// Problem constants (fixed by the reference file)
constexpr int C_  = 128;
constexpr int D_  = 32;
constexpr int H_  = 64;
constexpr int W_  = 64;
constexpr int PD = 4;
constexpr int PH = 7;
constexpr int PW = 7;
constexpr int SR = 2;          // sampling ratio
constexpr float SCALE = 0.25f; // spatial scale
constexpr int S_ = D_ * H_ * W_;       // 131072 spatial elements
constexpr int BINS_PER_ROI = PD * PH * PW; // 196

// ---------------------------------------------------------------------------
// Per-axis sampling: for pooled index p, compute the two sub-samples
// (s = p*SR + u, u in {0,1}) exactly as the reference does.
// ---------------------------------------------------------------------------
__device__ __forceinline__ void axis2(float start, float extent, int P, int p,
                                      int size, int lo[2], int hi[2],
                                      float w[2], bool v[2]) {
    float bin = extent / (float)P;
#pragma unroll
    for (int u = 0; u < 2; ++u) {
        float t = ((float)(p * SR + u) + 0.5f) / (float)SR;
        float coord = start + t * bin;
        v[u] = (coord >= -1.0f) && (coord <= (float)size);
        float cc = fminf(fmaxf(coord, 0.0f), (float)size - 1.0f);
        float fl = floorf(cc);
        lo[u] = (int)fl;
        hi[u] = min(lo[u] + 1, size - 1);
        w[u] = cc - fl;
    }
}

// ---------------------------------------------------------------------------
// Transpose [N, C, S] -> [N, S, C]  (channels-last), LDS-tiled 32x32.
// ---------------------------------------------------------------------------
__global__ void transpose_cl(const float* __restrict__ in,
                             float* __restrict__ outp) {
    __shared__ float tile[32][33];
    const int n  = blockIdx.z;
    const int s0 = blockIdx.x * 32;
    const int c0 = blockIdx.y * 32;
    const int tx = threadIdx.x; // 0..31
    const int ty = threadIdx.y; // 0..7

    const float* src = in   + (size_t)n * C_ * S_;
    float*       dst = outp + (size_t)n * C_ * S_;

#pragma unroll
    for (int i = 0; i < 4; ++i) {
        int cl = ty + i * 8;
        tile[cl][tx] = src[(size_t)(c0 + cl) * S_ + (s0 + tx)];
    }
    __syncthreads();
#pragma unroll
    for (int i = 0; i < 4; ++i) {
        int sl = ty + i * 8;
        dst[(size_t)(s0 + sl) * C_ + (c0 + tx)] = tile[tx][sl];
    }
}

// ---------------------------------------------------------------------------
// Main kernel (channels-last features): one block per pooled bin,
// one thread per channel. All coords/weights are block-uniform.
// ---------------------------------------------------------------------------
__global__ __launch_bounds__(C_) void roi_align_cl(
    const float* __restrict__ ft,   // [N, D, H, W, C]
    const float* __restrict__ rois, // [R, 7]
    float* __restrict__ out) {      // [R, C, PD, PH, PW]
    const int bin = blockIdx.x;
    const int c = threadIdx.x;

    int t = bin;
    const int pw = t % PW; t /= PW;
    const int ph = t % PH; t /= PH;
    const int pd = t % PD; t /= PD;
    const int r = t;

    const float* roi = rois + (size_t)r * 7;
    const int b = (int)roi[0];
    const float x1 = roi[1] * SCALE, y1 = roi[2] * SCALE, z1 = roi[3] * SCALE;
    const float x2 = roi[4] * SCALE, y2 = roi[5] * SCALE, z2 = roi[6] * SCALE;
    const float rd = fmaxf(z2 - z1, 1.0f);
    const float rh = fmaxf(y2 - y1, 1.0f);
    const float rw = fmaxf(x2 - x1, 1.0f);

    int zlo[2], zhi[2], ylo[2], yhi[2], xlo[2], xhi[2];
    float wz[2], wy[2], wx[2];
    bool vz[2], vy[2], vx[2];
    axis2(z1, rd, PD, pd, D_, zlo, zhi, wz, vz);
    axis2(y1, rh, PH, ph, H_, ylo, yhi, wy, vy);
    axis2(x1, rw, PW, pw, W_, xlo, xhi, wx, vx);

    float acc = 0.0f;
#pragma unroll
    for (int i = 0; i < 2; ++i) {
        if (!vz[i]) continue;
#pragma unroll
        for (int j = 0; j < 2; ++j) {
            if (!vy[j]) continue;
            // Row bases (without x, without channel)
            const size_t r00 = (((size_t)b * D_ + zlo[i]) * H_ + ylo[j]) * W_;
            const size_t r10 = (((size_t)b * D_ + zhi[i]) * H_ + ylo[j]) * W_;
            const size_t r01 = (((size_t)b * D_ + zlo[i]) * H_ + yhi[j]) * W_;
            const size_t r11 = (((size_t)b * D_ + zhi[i]) * H_ + yhi[j]) * W_;
            const float wz1 = wz[i], wz0 = 1.0f - wz1;
            const float wy1 = wy[j], wy0 = 1.0f - wy1;
#pragma unroll
            for (int k = 0; k < 2; ++k) {
                if (!vx[k]) continue;
                const float wx1 = wx[k], wx0 = 1.0f - wx1;
                const size_t xl = xlo[k], xh = xhi[k];
                const float f000 = ft[(r00 + xl) * C_ + c];
                const float f001 = ft[(r00 + xh) * C_ + c];
                const float f010 = ft[(r01 + xl) * C_ + c];
                const float f011 = ft[(r01 + xh) * C_ + c];
                const float f100 = ft[(r10 + xl) * C_ + c];
                const float f101 = ft[(r10 + xh) * C_ + c];
                const float f110 = ft[(r11 + xl) * C_ + c];
                const float f111 = ft[(r11 + xh) * C_ + c];
                acc += wz0 * (wy0 * (wx0 * f000 + wx1 * f001) +
                              wy1 * (wx0 * f010 + wx1 * f011)) +
                       wz1 * (wy0 * (wx0 * f100 + wx1 * f101) +
                              wy1 * (wx0 * f110 + wx1 * f111));
            }
        }
    }

    const size_t oidx =
        (((size_t)r * C_ + c) * PD + pd) * (PH * PW) + ph * PW + pw;
    out[oidx] = acc * (1.0f / (SR * SR * SR));
}

// ---------------------------------------------------------------------------
// Fallback: thread-per-output, native [N, C, D, H, W] layout (used only if
// the workspace is too small for the channels-last copy).
// ---------------------------------------------------------------------------
__global__ void roi_align_direct(const float* __restrict__ feat,
                                 const float* __restrict__ rois,
                                 float* __restrict__ out, int total) {
    const int tid = blockIdx.x * blockDim.x + threadIdx.x;
    if (tid >= total) return;

    int t = tid;
    const int pw = t % PW; t /= PW;
    const int ph = t % PH; t /= PH;
    const int pd = t % PD; t /= PD;
    const int c = t % C_;  t /= C_;
    const int r = t;

    const float* roi = rois + (size_t)r * 7;
    const int b = (int)roi[0];
    const float x1 = roi[1] * SCALE, y1 = roi[2] * SCALE, z1 = roi[3] * SCALE;
    const float x2 = roi[4] * SCALE, y2 = roi[5] * SCALE, z2 = roi[6] * SCALE;
    const float rd = fmaxf(z2 - z1, 1.0f);
    const float rh = fmaxf(y2 - y1, 1.0f);
    const float rw = fmaxf(x2 - x1, 1.0f);

    int zlo[2], zhi[2], ylo[2], yhi[2], xlo[2], xhi[2];
    float wz[2], wy[2], wx[2];
    bool vz[2], vy[2], vx[2];
    axis2(z1, rd, PD, pd, D_, zlo, zhi, wz, vz);
    axis2(y1, rh, PH, ph, H_, ylo, yhi, wy, vy);
    axis2(x1, rw, PW, pw, W_, xlo, xhi, wx, vx);

    const float* fc = feat + ((size_t)b * C_ + c) * S_;

    float acc = 0.0f;
#pragma unroll
    for (int i = 0; i < 2; ++i) {
        if (!vz[i]) continue;
#pragma unroll
        for (int j = 0; j < 2; ++j) {
            if (!vy[j]) continue;
            const size_t r00 = ((size_t)zlo[i] * H_ + ylo[j]) * W_;
            const size_t r10 = ((size_t)zhi[i] * H_ + ylo[j]) * W_;
            const size_t r01 = ((size_t)zlo[i] * H_ + yhi[j]) * W_;
            const size_t r11 = ((size_t)zhi[i] * H_ + yhi[j]) * W_;
            const float wz1 = wz[i], wz0 = 1.0f - wz1;
            const float wy1 = wy[j], wy0 = 1.0f - wy1;
#pragma unroll
            for (int k = 0; k < 2; ++k) {
                if (!vx[k]) continue;
                const float wx1 = wx[k], wx0 = 1.0f - wx1;
                const float f000 = fc[r00 + xlo[k]];
                const float f001 = fc[r00 + xhi[k]];
                const float f010 = fc[r01 + xlo[k]];
                const float f011 = fc[r01 + xhi[k]];
                const float f100 = fc[r10 + xlo[k]];
                const float f101 = fc[r10 + xhi[k]];
                const float f110 = fc[r11 + xlo[k]];
                const float f111 = fc[r11 + xhi[k]];
                acc += wz0 * (wy0 * (wx0 * f000 + wx1 * f001) +
                              wy1 * (wx0 * f010 + wx1 * f011)) +
                       wz1 * (wy0 * (wx0 * f100 + wx1 * f101) +
                              wy1 * (wx0 * f110 + wx1 * f111));
            }
        }
    }

    out[tid] = acc * (1.0f / (SR * SR * SR));
}

extern "C" void kernel_launch(void* const* d_in, const int* in_sizes, int n_in,
                              void* d_out, int out_size, void* d_ws,
                              size_t ws_size, hipStream_t stream) {
    const float* features = (const float*)d_in[0];
    const float* rois = (const float*)d_in[1];
    float* out = (float*)d_out;

    const int R = in_sizes[1] / 7;
    const int N = in_sizes[0] / (C_ * S_);
    const size_t need = (size_t)in_sizes[0] * sizeof(float);

    if (ws_size >= need) {
        float* ft = (float*)d_ws; // [N, D, H, W, C]
        dim3 tg(S_ / 32, C_ / 32, N);
        dim3 tb(32, 8, 1);
        transpose_cl<<<tg, tb, 0, stream>>>(features, ft);

        const int bins = R * BINS_PER_ROI;
        roi_align_cl<<<bins, C_, 0, stream>>>(ft, rois, out);
    } else {
        const int total = R * C_ * BINS_PER_ROI;
        const int threads = 256;
        const int blocks = (total + threads - 1) / threads;
        roi_align_direct<<<blocks, threads, 0, stream>>>(features, rois, out,
                                                         total);
    }
}

// Round 2
// 351.358 us; speedup vs baseline: 1.1486x; 1.1486x over previous
//
#include <hip/hip_runtime.h>

// Problem constants (fixed by the reference file)
constexpr int C_  = 128;
constexpr int D_  = 32;
constexpr int H_  = 64;
constexpr int W_  = 64;
constexpr int PD = 4;
constexpr int PH = 7;
constexpr int PW = 7;
constexpr int SR = 2;          // sampling ratio
constexpr float SCALE = 0.25f; // spatial scale
constexpr int S_ = D_ * H_ * W_;           // 131072 spatial elements
constexpr int BINS_PER_ROI = PD * PH * PW; // 196

// ---------------------------------------------------------------------------
// Per-axis sampling (matches reference _axis + sample_coords exactly)
// ---------------------------------------------------------------------------
__device__ __forceinline__ void axis2(float start, float extent, int P, int p,
                                      int size, int lo[2], int hi[2],
                                      float w[2], bool v[2]) {
    float bin = extent / (float)P;
#pragma unroll
    for (int u = 0; u < 2; ++u) {
        float t = ((float)(p * SR + u) + 0.5f) / (float)SR;
        float coord = start + t * bin;
        v[u] = (coord >= -1.0f) && (coord <= (float)size);
        float cc = fminf(fmaxf(coord, 0.0f), (float)size - 1.0f);
        float fl = floorf(cc);
        lo[u] = (int)fl;
        hi[u] = min(lo[u] + 1, size - 1);
        w[u] = cc - fl;
    }
}

// ---------------------------------------------------------------------------
// Feature transpose [N, C, S] -> [N, S, C], 64x64 tiles, float4 both sides.
// LDS tile[s][c], row pad 65 floats: load-phase scattered writes and
// store-phase scalar reads are both <=2-way bank conflicts (free).
// ---------------------------------------------------------------------------
__global__ __launch_bounds__(256) void transpose_cl4(
    const float* __restrict__ in, float* __restrict__ outp) {
    __shared__ float tile[64][65];
    const int n  = blockIdx.z;
    const int s0 = blockIdx.x * 64;
    const int c0 = blockIdx.y * 64;
    const int t  = threadIdx.x;

    const float* src = in   + (size_t)n * C_ * S_;
    float*       dst = outp + (size_t)n * C_ * S_;

    // Load phase: coalesced float4 along S.
    {
        const int c_l = t >> 4;        // 0..15
        const int s4  = (t & 15) * 4;  // 0..60
#pragma unroll
        for (int i = 0; i < 4; ++i) {
            const int c = c_l + 16 * i;
            const float4 v =
                *(const float4*)&src[(size_t)(c0 + c) * S_ + (s0 + s4)];
            tile[s4 + 0][c] = v.x;
            tile[s4 + 1][c] = v.y;
            tile[s4 + 2][c] = v.z;
            tile[s4 + 3][c] = v.w;
        }
    }
    __syncthreads();
    // Store phase: coalesced float4 along C.
    {
        const int s_l = t >> 4;        // 0..15
        const int c4  = (t & 15) * 4;  // 0..60
#pragma unroll
        for (int i = 0; i < 4; ++i) {
            const int s = s_l + 16 * i;
            float4 v;
            v.x = tile[s][c4 + 0];
            v.y = tile[s][c4 + 1];
            v.z = tile[s][c4 + 2];
            v.w = tile[s][c4 + 3];
            *(float4*)&dst[(size_t)(s0 + s) * C_ + (c0 + c4)] = v;
        }
    }
}

// ---------------------------------------------------------------------------
// Main kernel (channels-last): 8 bins per block, 32 lanes per bin, each lane
// a float4 of channels. All global loads/stores are full-line coalesced.
// Writes [R, 196, C] to ws2.
// ---------------------------------------------------------------------------
__global__ __launch_bounds__(256) void roi_align_cl4(
    const float* __restrict__ ft,   // [N, D, H, W, C]
    const float* __restrict__ rois, // [R, 7]
    float* __restrict__ ws2) {      // [R, 196, C]
    const int t = threadIdx.x;
    const int bing = blockIdx.x * 8 + (t >> 5); // global bin index
    const int c4 = (t & 31) * 4;

    const int r = bing / BINS_PER_ROI;
    const int bin = bing - r * BINS_PER_ROI;
    const int pd = bin / (PH * PW);
    const int rem = bin - pd * (PH * PW);
    const int ph = rem / PW;
    const int pw = rem - ph * PW;

    const float* roi = rois + (size_t)r * 7;
    const int b = (int)roi[0];
    const float x1 = roi[1] * SCALE, y1 = roi[2] * SCALE, z1 = roi[3] * SCALE;
    const float x2 = roi[4] * SCALE, y2 = roi[5] * SCALE, z2 = roi[6] * SCALE;
    const float rd = fmaxf(z2 - z1, 1.0f);
    const float rh = fmaxf(y2 - y1, 1.0f);
    const float rw = fmaxf(x2 - x1, 1.0f);

    int zlo[2], zhi[2], ylo[2], yhi[2], xlo[2], xhi[2];
    float wz[2], wy[2], wx[2];
    bool vz[2], vy[2], vx[2];
    axis2(z1, rd, PD, pd, D_, zlo, zhi, wz, vz);
    axis2(y1, rh, PH, ph, H_, ylo, yhi, wy, vy);
    axis2(x1, rw, PW, pw, W_, xlo, xhi, wx, vx);

    float4 acc = make_float4(0.f, 0.f, 0.f, 0.f);
#pragma unroll
    for (int i = 0; i < 2; ++i) {
        if (!vz[i]) continue;
        const float wz1 = wz[i], wz0 = 1.0f - wz1;
#pragma unroll
        for (int j = 0; j < 2; ++j) {
            if (!vy[j]) continue;
            const float wy1 = wy[j], wy0 = 1.0f - wy1;
            const size_t r00 = (((size_t)b * D_ + zlo[i]) * H_ + ylo[j]) * W_;
            const size_t r10 = (((size_t)b * D_ + zhi[i]) * H_ + ylo[j]) * W_;
            const size_t r01 = (((size_t)b * D_ + zlo[i]) * H_ + yhi[j]) * W_;
            const size_t r11 = (((size_t)b * D_ + zhi[i]) * H_ + yhi[j]) * W_;
#pragma unroll
            for (int k = 0; k < 2; ++k) {
                if (!vx[k]) continue;
                const float wx1 = wx[k], wx0 = 1.0f - wx1;
                const size_t xl = xlo[k], xh = xhi[k];
                const float4 f000 = *(const float4*)&ft[(r00 + xl) * C_ + c4];
                const float4 f001 = *(const float4*)&ft[(r00 + xh) * C_ + c4];
                const float4 f010 = *(const float4*)&ft[(r01 + xl) * C_ + c4];
                const float4 f011 = *(const float4*)&ft[(r01 + xh) * C_ + c4];
                const float4 f100 = *(const float4*)&ft[(r10 + xl) * C_ + c4];
                const float4 f101 = *(const float4*)&ft[(r10 + xh) * C_ + c4];
                const float4 f110 = *(const float4*)&ft[(r11 + xl) * C_ + c4];
                const float4 f111 = *(const float4*)&ft[(r11 + xh) * C_ + c4];
                const float w000 = wz0 * wy0 * wx0, w001 = wz0 * wy0 * wx1;
                const float w010 = wz0 * wy1 * wx0, w011 = wz0 * wy1 * wx1;
                const float w100 = wz1 * wy0 * wx0, w101 = wz1 * wy0 * wx1;
                const float w110 = wz1 * wy1 * wx0, w111 = wz1 * wy1 * wx1;
                acc.x += w000 * f000.x + w001 * f001.x + w010 * f010.x +
                         w011 * f011.x + w100 * f100.x + w101 * f101.x +
                         w110 * f110.x + w111 * f111.x;
                acc.y += w000 * f000.y + w001 * f001.y + w010 * f010.y +
                         w011 * f011.y + w100 * f100.y + w101 * f101.y +
                         w110 * f110.y + w111 * f111.y;
                acc.z += w000 * f000.z + w001 * f001.z + w010 * f010.z +
                         w011 * f011.z + w100 * f100.z + w101 * f101.z +
                         w110 * f110.z + w111 * f111.z;
                acc.w += w000 * f000.w + w001 * f001.w + w010 * f010.w +
                         w011 * f011.w + w100 * f100.w + w101 * f101.w +
                         w110 * f110.w + w111 * f111.w;
            }
        }
    }

    const float s = 1.0f / (SR * SR * SR);
    acc.x *= s; acc.y *= s; acc.z *= s; acc.w *= s;
    *(float4*)&ws2[(size_t)bing * C_ + c4] = acc;
}

// ---------------------------------------------------------------------------
// Reorder [R, 196, C] -> [R, C, 196], tiled transpose, coalesced both sides.
// ---------------------------------------------------------------------------
__global__ void reorder_out(const float* __restrict__ in,
                            float* __restrict__ outp) {
    __shared__ float tile[32][33];
    const int r  = blockIdx.z;
    const int b0 = blockIdx.x * 32; // bin tile
    const int c0 = blockIdx.y * 32; // channel tile
    const int tx = threadIdx.x;     // 0..31
    const int ty = threadIdx.y;     // 0..7

    const float* src = in + (size_t)r * BINS_PER_ROI * C_;
    float* dst = outp + (size_t)r * BINS_PER_ROI * C_;

#pragma unroll
    for (int i = 0; i < 4; ++i) {
        const int row = ty + i * 8; // bin within tile
        if (b0 + row < BINS_PER_ROI)
            tile[row][tx] = src[(size_t)(b0 + row) * C_ + (c0 + tx)];
    }
    __syncthreads();
#pragma unroll
    for (int i = 0; i < 4; ++i) {
        const int row = ty + i * 8; // channel within tile
        if (b0 + tx < BINS_PER_ROI)
            dst[(size_t)(c0 + row) * BINS_PER_ROI + (b0 + tx)] =
                tile[tx][row];
    }
}

// ---------------------------------------------------------------------------
// Mid path: one block per bin, direct (strided) out store. Used only if ws
// fits the CL features but not the extra [R,196,C] buffer.
// ---------------------------------------------------------------------------
__global__ __launch_bounds__(C_) void roi_align_cl(
    const float* __restrict__ ft, const float* __restrict__ rois,
    float* __restrict__ out) {
    const int bin = blockIdx.x;
    const int c = threadIdx.x;
    int t = bin;
    const int pw = t % PW; t /= PW;
    const int ph = t % PH; t /= PH;
    const int pd = t % PD; t /= PD;
    const int r = t;

    const float* roi = rois + (size_t)r * 7;
    const int b = (int)roi[0];
    const float x1 = roi[1] * SCALE, y1 = roi[2] * SCALE, z1 = roi[3] * SCALE;
    const float x2 = roi[4] * SCALE, y2 = roi[5] * SCALE, z2 = roi[6] * SCALE;
    const float rd = fmaxf(z2 - z1, 1.0f);
    const float rh = fmaxf(y2 - y1, 1.0f);
    const float rw = fmaxf(x2 - x1, 1.0f);

    int zlo[2], zhi[2], ylo[2], yhi[2], xlo[2], xhi[2];
    float wz[2], wy[2], wx[2];
    bool vz[2], vy[2], vx[2];
    axis2(z1, rd, PD, pd, D_, zlo, zhi, wz, vz);
    axis2(y1, rh, PH, ph, H_, ylo, yhi, wy, vy);
    axis2(x1, rw, PW, pw, W_, xlo, xhi, wx, vx);

    float acc = 0.0f;
#pragma unroll
    for (int i = 0; i < 2; ++i) {
        if (!vz[i]) continue;
#pragma unroll
        for (int j = 0; j < 2; ++j) {
            if (!vy[j]) continue;
            const size_t r00 = (((size_t)b * D_ + zlo[i]) * H_ + ylo[j]) * W_;
            const size_t r10 = (((size_t)b * D_ + zhi[i]) * H_ + ylo[j]) * W_;
            const size_t r01 = (((size_t)b * D_ + zlo[i]) * H_ + yhi[j]) * W_;
            const size_t r11 = (((size_t)b * D_ + zhi[i]) * H_ + yhi[j]) * W_;
            const float wz1 = wz[i], wz0 = 1.0f - wz1;
            const float wy1 = wy[j], wy0 = 1.0f - wy1;
#pragma unroll
            for (int k = 0; k < 2; ++k) {
                if (!vx[k]) continue;
                const float wx1 = wx[k], wx0 = 1.0f - wx1;
                const size_t xl = xlo[k], xh = xhi[k];
                const float f000 = ft[(r00 + xl) * C_ + c];
                const float f001 = ft[(r00 + xh) * C_ + c];
                const float f010 = ft[(r01 + xl) * C_ + c];
                const float f011 = ft[(r01 + xh) * C_ + c];
                const float f100 = ft[(r10 + xl) * C_ + c];
                const float f101 = ft[(r10 + xh) * C_ + c];
                const float f110 = ft[(r11 + xl) * C_ + c];
                const float f111 = ft[(r11 + xh) * C_ + c];
                acc += wz0 * (wy0 * (wx0 * f000 + wx1 * f001) +
                              wy1 * (wx0 * f010 + wx1 * f011)) +
                       wz1 * (wy0 * (wx0 * f100 + wx1 * f101) +
                              wy1 * (wx0 * f110 + wx1 * f111));
            }
        }
    }
    const size_t oidx =
        (((size_t)r * C_ + c) * PD + pd) * (PH * PW) + ph * PW + pw;
    out[oidx] = acc * (1.0f / (SR * SR * SR));
}

// ---------------------------------------------------------------------------
// Fallback: thread-per-output, native layout (tiny ws only).
// ---------------------------------------------------------------------------
__global__ void roi_align_direct(const float* __restrict__ feat,
                                 const float* __restrict__ rois,
                                 float* __restrict__ out, int total) {
    const int tid = blockIdx.x * blockDim.x + threadIdx.x;
    if (tid >= total) return;
    int t = tid;
    const int pw = t % PW; t /= PW;
    const int ph = t % PH; t /= PH;
    const int pd = t % PD; t /= PD;
    const int c = t % C_;  t /= C_;
    const int r = t;

    const float* roi = rois + (size_t)r * 7;
    const int b = (int)roi[0];
    const float x1 = roi[1] * SCALE, y1 = roi[2] * SCALE, z1 = roi[3] * SCALE;
    const float x2 = roi[4] * SCALE, y2 = roi[5] * SCALE, z2 = roi[6] * SCALE;
    const float rd = fmaxf(z2 - z1, 1.0f);
    const float rh = fmaxf(y2 - y1, 1.0f);
    const float rw = fmaxf(x2 - x1, 1.0f);

    int zlo[2], zhi[2], ylo[2], yhi[2], xlo[2], xhi[2];
    float wz[2], wy[2], wx[2];
    bool vz[2], vy[2], vx[2];
    axis2(z1, rd, PD, pd, D_, zlo, zhi, wz, vz);
    axis2(y1, rh, PH, ph, H_, ylo, yhi, wy, vy);
    axis2(x1, rw, PW, pw, W_, xlo, xhi, wx, vx);

    const float* fc = feat + ((size_t)b * C_ + c) * S_;
    float acc = 0.0f;
#pragma unroll
    for (int i = 0; i < 2; ++i) {
        if (!vz[i]) continue;
#pragma unroll
        for (int j = 0; j < 2; ++j) {
            if (!vy[j]) continue;
            const size_t r00 = ((size_t)zlo[i] * H_ + ylo[j]) * W_;
            const size_t r10 = ((size_t)zhi[i] * H_ + ylo[j]) * W_;
            const size_t r01 = ((size_t)zlo[i] * H_ + yhi[j]) * W_;
            const size_t r11 = ((size_t)zhi[i] * H_ + yhi[j]) * W_;
            const float wz1 = wz[i], wz0 = 1.0f - wz1;
            const float wy1 = wy[j], wy0 = 1.0f - wy1;
#pragma unroll
            for (int k = 0; k < 2; ++k) {
                if (!vx[k]) continue;
                const float wx1 = wx[k], wx0 = 1.0f - wx1;
                acc += wz0 * (wy0 * (wx0 * fc[r00 + xlo[k]] + wx1 * fc[r00 + xhi[k]]) +
                              wy1 * (wx0 * fc[r01 + xlo[k]] + wx1 * fc[r01 + xhi[k]])) +
                       wz1 * (wy0 * (wx0 * fc[r10 + xlo[k]] + wx1 * fc[r10 + xhi[k]]) +
                              wy1 * (wx0 * fc[r11 + xlo[k]] + wx1 * fc[r11 + xhi[k]]));
            }
        }
    }
    out[tid] = acc * (1.0f / (SR * SR * SR));
}

extern "C" void kernel_launch(void* const* d_in, const int* in_sizes, int n_in,
                              void* d_out, int out_size, void* d_ws,
                              size_t ws_size, hipStream_t stream) {
    const float* features = (const float*)d_in[0];
    const float* rois = (const float*)d_in[1];
    float* out = (float*)d_out;

    const int R = in_sizes[1] / 7;
    const int N = in_sizes[0] / (C_ * S_);
    const size_t feat_bytes = (size_t)in_sizes[0] * sizeof(float);
    const size_t ws2_bytes = (size_t)R * BINS_PER_ROI * C_ * sizeof(float);

    if (ws_size >= feat_bytes + ws2_bytes) {
        float* ft = (float*)d_ws;                      // [N, D, H, W, C]
        float* ws2 = (float*)((char*)d_ws + feat_bytes); // [R, 196, C]

        dim3 tg(S_ / 64, C_ / 64, N);
        transpose_cl4<<<tg, 256, 0, stream>>>(features, ft);

        const int bins = R * BINS_PER_ROI; // 50176, divisible by 8
        roi_align_cl4<<<bins / 8, 256, 0, stream>>>(ft, rois, ws2);

        dim3 rg((BINS_PER_ROI + 31) / 32, C_ / 32, R);
        dim3 rb(32, 8, 1);
        reorder_out<<<rg, rb, 0, stream>>>(ws2, out);
    } else if (ws_size >= feat_bytes) {
        float* ft = (float*)d_ws;
        dim3 tg(S_ / 64, C_ / 64, N);
        transpose_cl4<<<tg, 256, 0, stream>>>(features, ft);
        roi_align_cl<<<R * BINS_PER_ROI, C_, 0, stream>>>(ft, rois, out);
    } else {
        const int total = R * C_ * BINS_PER_ROI;
        roi_align_direct<<<(total + 255) / 256, 256, 0, stream>>>(
            features, rois, out, total);
    }
}

// Round 3
// 270.586 us; speedup vs baseline: 1.4915x; 1.2985x over previous
//
#include <hip/hip_runtime.h>

// Problem constants (fixed by the reference file)
constexpr int C_  = 128;
constexpr int D_  = 32;
constexpr int H_  = 64;
constexpr int W_  = 64;
constexpr int PD = 4;
constexpr int PH = 7;
constexpr int PW = 7;
constexpr int SR = 2;          // sampling ratio
constexpr float SCALE = 0.25f; // spatial scale
constexpr int S_ = D_ * H_ * W_;           // 131072 spatial elements
constexpr int BINS_PER_ROI = PD * PH * PW; // 196
constexpr int SLAB = PH * PW;              // 49 bins per (roi, pd) slab

// ---------------------------------------------------------------------------
// Per-axis sampling (matches reference _axis + sample_coords exactly)
// ---------------------------------------------------------------------------
__device__ __forceinline__ void axis2(float start, float extent, int P, int p,
                                      int size, int lo[2], int hi[2],
                                      float w[2], bool v[2]) {
    float bin = extent / (float)P;
#pragma unroll
    for (int u = 0; u < 2; ++u) {
        float t = ((float)(p * SR + u) + 0.5f) / (float)SR;
        float coord = start + t * bin;
        v[u] = (coord >= -1.0f) && (coord <= (float)size);
        float cc = fminf(fmaxf(coord, 0.0f), (float)size - 1.0f);
        float fl = floorf(cc);
        lo[u] = (int)fl;
        hi[u] = min(lo[u] + 1, size - 1);
        w[u] = cc - fl;
    }
}

// float -> bf16 (round-to-nearest-even; inputs are finite)
__device__ __forceinline__ unsigned short f2bf(float f) {
    unsigned int u = __float_as_uint(f);
    u += 0x7fffu + ((u >> 16) & 1u);
    return (unsigned short)(u >> 16);
}

// unpack 4 bf16 (as uint2) -> float4
__device__ __forceinline__ float4 bf4(uint2 v) {
    float4 f;
    f.x = __uint_as_float(v.x << 16);
    f.y = __uint_as_float(v.x & 0xffff0000u);
    f.z = __uint_as_float(v.y << 16);
    f.w = __uint_as_float(v.y & 0xffff0000u);
    return f;
}

// ---------------------------------------------------------------------------
// Transpose + cast: [N, C, S] f32 -> [N, S, C] bf16.
// s-tile of 64, full C=128 per block => dst writes are 64 x 256 B contiguous.
// ---------------------------------------------------------------------------
__global__ __launch_bounds__(256) void transpose_bf16(
    const float* __restrict__ in, unsigned short* __restrict__ outp) {
    __shared__ __align__(16) unsigned short tile[64][132]; // [s][c], pad->free-ish
    const int n  = blockIdx.y;
    const int s0 = blockIdx.x * 64;
    const int t  = threadIdx.x;

    const float* src = in + (size_t)n * C_ * S_;
    unsigned short* dst = outp + (size_t)n * C_ * S_;

    // Load phase: coalesced float4 along S, convert, scatter into LDS.
    {
        const int cl = t >> 4;        // 0..15
        const int s4 = (t & 15) * 4;  // 0..60
#pragma unroll
        for (int p = 0; p < 8; ++p) {
            const int c = cl + 16 * p;
            const float4 v =
                *(const float4*)&src[(size_t)c * S_ + (s0 + s4)];
            tile[s4 + 0][c] = f2bf(v.x);
            tile[s4 + 1][c] = f2bf(v.y);
            tile[s4 + 2][c] = f2bf(v.z);
            tile[s4 + 3][c] = f2bf(v.w);
        }
    }
    __syncthreads();
    // Store phase: contiguous 256 B per 32-lane group along C.
    {
        const int sl = t >> 5;        // 0..7
        const int c4 = (t & 31) * 4;  // 0..124
#pragma unroll
        for (int p = 0; p < 8; ++p) {
            const int s = sl + 8 * p;
            const unsigned short a0 = tile[s][c4 + 0];
            const unsigned short a1 = tile[s][c4 + 1];
            const unsigned short a2 = tile[s][c4 + 2];
            const unsigned short a3 = tile[s][c4 + 3];
            uint2 v;
            v.x = (unsigned int)a0 | ((unsigned int)a1 << 16);
            v.y = (unsigned int)a2 | ((unsigned int)a3 << 16);
            *(uint2*)&dst[(size_t)(s0 + s) * C_ + c4] = v;
        }
    }
}

// ---------------------------------------------------------------------------
// Main kernel: one block per (roi, pd) slab. 32 lanes per bin (4 ch each),
// 8 bin-slots in flight; each thread loops over its slots, writes results to
// an LDS [49][C] tile, then the block stores the slab in FINAL output layout
// (contiguous 49-float runs per channel). bf16 feature gathers, 256 B/group.
// XCD swizzle: all 4 slabs of an ROI share blockIdx%8 -> same XCD L2.
// ---------------------------------------------------------------------------
__global__ __launch_bounds__(256) void roi_align_slab(
    const unsigned short* __restrict__ ft, // [N, D, H, W, C] bf16
    const float* __restrict__ rois,        // [R, 7]
    float* __restrict__ out,               // [R, C, PD, PH, PW]
    int R) {
    __shared__ __align__(16) float tile[SLAB][132];

    int r, pd;
    if ((R & 7) == 0) {
        const int xcd = blockIdx.x & 7;
        const int q = blockIdx.x >> 3;
        pd = q & 3;
        r = ((q >> 2) << 3) + xcd;
    } else {
        r = blockIdx.x >> 2;
        pd = blockIdx.x & 3;
    }

    const int t = threadIdx.x;
    const int grp = t >> 5;       // slot group 0..7
    const int c4 = (t & 31) * 4;  // channel base

    const float* roi = rois + (size_t)r * 7;
    const int b = (int)roi[0];
    const float x1 = roi[1] * SCALE, y1 = roi[2] * SCALE, z1 = roi[3] * SCALE;
    const float x2 = roi[4] * SCALE, y2 = roi[5] * SCALE, z2 = roi[6] * SCALE;
    const float rd = fmaxf(z2 - z1, 1.0f);
    const float rh = fmaxf(y2 - y1, 1.0f);
    const float rw = fmaxf(x2 - x1, 1.0f);

    int zlo[2], zhi[2];
    float wz[2];
    bool vz[2];
    axis2(z1, rd, PD, pd, D_, zlo, zhi, wz, vz);

#pragma unroll 1
    for (int k = 0; k < 7; ++k) {
        const int slot = grp + 8 * k;
        if (slot < SLAB) {
            const int ph = slot / PW;
            const int pw = slot - ph * PW;

            int ylo[2], yhi[2], xlo[2], xhi[2];
            float wy[2], wx[2];
            bool vy[2], vx[2];
            axis2(y1, rh, PH, ph, H_, ylo, yhi, wy, vy);
            axis2(x1, rw, PW, pw, W_, xlo, xhi, wx, vx);

            float4 acc = make_float4(0.f, 0.f, 0.f, 0.f);
#pragma unroll
            for (int i = 0; i < 2; ++i) {
                if (!vz[i]) continue;
                const float wz1 = wz[i], wz0 = 1.0f - wz1;
#pragma unroll
                for (int j = 0; j < 2; ++j) {
                    if (!vy[j]) continue;
                    const float wy1 = wy[j], wy0 = 1.0f - wy1;
                    const size_t r00 =
                        (((size_t)b * D_ + zlo[i]) * H_ + ylo[j]) * W_;
                    const size_t r10 =
                        (((size_t)b * D_ + zhi[i]) * H_ + ylo[j]) * W_;
                    const size_t r01 =
                        (((size_t)b * D_ + zlo[i]) * H_ + yhi[j]) * W_;
                    const size_t r11 =
                        (((size_t)b * D_ + zhi[i]) * H_ + yhi[j]) * W_;
#pragma unroll
                    for (int kk = 0; kk < 2; ++kk) {
                        if (!vx[kk]) continue;
                        const float wx1 = wx[kk], wx0 = 1.0f - wx1;
                        const size_t xl = xlo[kk], xh = xhi[kk];
                        const float4 f000 =
                            bf4(*(const uint2*)&ft[(r00 + xl) * C_ + c4]);
                        const float4 f001 =
                            bf4(*(const uint2*)&ft[(r00 + xh) * C_ + c4]);
                        const float4 f010 =
                            bf4(*(const uint2*)&ft[(r01 + xl) * C_ + c4]);
                        const float4 f011 =
                            bf4(*(const uint2*)&ft[(r01 + xh) * C_ + c4]);
                        const float4 f100 =
                            bf4(*(const uint2*)&ft[(r10 + xl) * C_ + c4]);
                        const float4 f101 =
                            bf4(*(const uint2*)&ft[(r10 + xh) * C_ + c4]);
                        const float4 f110 =
                            bf4(*(const uint2*)&ft[(r11 + xl) * C_ + c4]);
                        const float4 f111 =
                            bf4(*(const uint2*)&ft[(r11 + xh) * C_ + c4]);
                        const float w000 = wz0 * wy0 * wx0,
                                    w001 = wz0 * wy0 * wx1;
                        const float w010 = wz0 * wy1 * wx0,
                                    w011 = wz0 * wy1 * wx1;
                        const float w100 = wz1 * wy0 * wx0,
                                    w101 = wz1 * wy0 * wx1;
                        const float w110 = wz1 * wy1 * wx0,
                                    w111 = wz1 * wy1 * wx1;
                        acc.x += w000 * f000.x + w001 * f001.x +
                                 w010 * f010.x + w011 * f011.x +
                                 w100 * f100.x + w101 * f101.x +
                                 w110 * f110.x + w111 * f111.x;
                        acc.y += w000 * f000.y + w001 * f001.y +
                                 w010 * f010.y + w011 * f011.y +
                                 w100 * f100.y + w101 * f101.y +
                                 w110 * f110.y + w111 * f111.y;
                        acc.z += w000 * f000.z + w001 * f001.z +
                                 w010 * f010.z + w011 * f011.z +
                                 w100 * f100.z + w101 * f101.z +
                                 w110 * f110.z + w111 * f111.z;
                        acc.w += w000 * f000.w + w001 * f001.w +
                                 w010 * f010.w + w011 * f011.w +
                                 w100 * f100.w + w101 * f101.w +
                                 w110 * f110.w + w111 * f111.w;
                    }
                }
            }
            const float s = 1.0f / (SR * SR * SR);
            acc.x *= s; acc.y *= s; acc.z *= s; acc.w *= s;
            *(float4*)&tile[slot][c4] = acc;
        }
    }

    __syncthreads();

    // Store the slab in final layout: out[r][c][pd*49 + o], contiguous o-runs.
    const size_t obase = (size_t)r * C_ * BINS_PER_ROI + (size_t)pd * SLAB;
#pragma unroll 1
    for (int idx = t; idx < C_ * SLAB; idx += 256) {
        const int c = idx / SLAB;
        const int o = idx - c * SLAB;
        out[obase + (size_t)c * BINS_PER_ROI + o] = tile[o][c];
    }
}

// ---------------------------------------------------------------------------
// Fallback: thread-per-output, native layout (tiny ws only).
// ---------------------------------------------------------------------------
__global__ void roi_align_direct(const float* __restrict__ feat,
                                 const float* __restrict__ rois,
                                 float* __restrict__ out, int total) {
    const int tid = blockIdx.x * blockDim.x + threadIdx.x;
    if (tid >= total) return;
    int t = tid;
    const int pw = t % PW; t /= PW;
    const int ph = t % PH; t /= PH;
    const int pd = t % PD; t /= PD;
    const int c = t % C_;  t /= C_;
    const int r = t;

    const float* roi = rois + (size_t)r * 7;
    const int b = (int)roi[0];
    const float x1 = roi[1] * SCALE, y1 = roi[2] * SCALE, z1 = roi[3] * SCALE;
    const float x2 = roi[4] * SCALE, y2 = roi[5] * SCALE, z2 = roi[6] * SCALE;
    const float rd = fmaxf(z2 - z1, 1.0f);
    const float rh = fmaxf(y2 - y1, 1.0f);
    const float rw = fmaxf(x2 - x1, 1.0f);

    int zlo[2], zhi[2], ylo[2], yhi[2], xlo[2], xhi[2];
    float wz[2], wy[2], wx[2];
    bool vz[2], vy[2], vx[2];
    axis2(z1, rd, PD, pd, D_, zlo, zhi, wz, vz);
    axis2(y1, rh, PH, ph, H_, ylo, yhi, wy, vy);
    axis2(x1, rw, PW, pw, W_, xlo, xhi, wx, vx);

    const float* fc = feat + ((size_t)b * C_ + c) * S_;
    float acc = 0.0f;
#pragma unroll
    for (int i = 0; i < 2; ++i) {
        if (!vz[i]) continue;
#pragma unroll
        for (int j = 0; j < 2; ++j) {
            if (!vy[j]) continue;
            const size_t r00 = ((size_t)zlo[i] * H_ + ylo[j]) * W_;
            const size_t r10 = ((size_t)zhi[i] * H_ + ylo[j]) * W_;
            const size_t r01 = ((size_t)zlo[i] * H_ + yhi[j]) * W_;
            const size_t r11 = ((size_t)zhi[i] * H_ + yhi[j]) * W_;
            const float wz1 = wz[i], wz0 = 1.0f - wz1;
            const float wy1 = wy[j], wy0 = 1.0f - wy1;
#pragma unroll
            for (int k = 0; k < 2; ++k) {
                if (!vx[k]) continue;
                const float wx1 = wx[k], wx0 = 1.0f - wx1;
                acc += wz0 * (wy0 * (wx0 * fc[r00 + xlo[k]] + wx1 * fc[r00 + xhi[k]]) +
                              wy1 * (wx0 * fc[r01 + xlo[k]] + wx1 * fc[r01 + xhi[k]])) +
                       wz1 * (wy0 * (wx0 * fc[r10 + xlo[k]] + wx1 * fc[r10 + xhi[k]]) +
                              wy1 * (wx0 * fc[r11 + xlo[k]] + wx1 * fc[r11 + xhi[k]]));
            }
        }
    }
    out[tid] = acc * (1.0f / (SR * SR * SR));
}

extern "C" void kernel_launch(void* const* d_in, const int* in_sizes, int n_in,
                              void* d_out, int out_size, void* d_ws,
                              size_t ws_size, hipStream_t stream) {
    const float* features = (const float*)d_in[0];
    const float* rois = (const float*)d_in[1];
    float* out = (float*)d_out;

    const int R = in_sizes[1] / 7;
    const int N = in_sizes[0] / (C_ * S_);
    const size_t need = (size_t)in_sizes[0] * sizeof(unsigned short);

    if (ws_size >= need) {
        unsigned short* ft = (unsigned short*)d_ws; // [N, D, H, W, C] bf16

        dim3 tg(S_ / 64, N);
        transpose_bf16<<<tg, 256, 0, stream>>>(features, ft);

        roi_align_slab<<<R * PD, 256, 0, stream>>>(ft, rois, out, R);
    } else {
        const int total = R * C_ * BINS_PER_ROI;
        roi_align_direct<<<(total + 255) / 256, 256, 0, stream>>>(
            features, rois, out, total);
    }
}

// Round 4
// 267.987 us; speedup vs baseline: 1.5060x; 1.0097x over previous
//
#include <hip/hip_runtime.h>

// Problem constants (fixed by the reference file)
constexpr int C_  = 128;
constexpr int D_  = 32;
constexpr int H_  = 64;
constexpr int W_  = 64;
constexpr int PD = 4;
constexpr int PH = 7;
constexpr int PW = 7;
constexpr int SR = 2;          // sampling ratio
constexpr float SCALE = 0.25f; // spatial scale
constexpr int S_ = D_ * H_ * W_;           // 131072 spatial elements
constexpr int BINS_PER_ROI = PD * PH * PW; // 196
constexpr int SLAB = PH * PW;              // 49 bins per (roi, pd) slab

// ---------------------------------------------------------------------------
// Per-axis sampling (matches reference _axis + sample_coords exactly)
// ---------------------------------------------------------------------------
__device__ __forceinline__ void axis2(float start, float extent, int P, int p,
                                      int size, int lo[2], int hi[2],
                                      float w[2], bool v[2]) {
    float bin = extent / (float)P;
#pragma unroll
    for (int u = 0; u < 2; ++u) {
        float t = ((float)(p * SR + u) + 0.5f) / (float)SR;
        float coord = start + t * bin;
        v[u] = (coord >= -1.0f) && (coord <= (float)size);
        float cc = fminf(fmaxf(coord, 0.0f), (float)size - 1.0f);
        float fl = floorf(cc);
        lo[u] = (int)fl;
        hi[u] = min(lo[u] + 1, size - 1);
        w[u] = cc - fl;
    }
}

// float -> bf16 bits (round-to-nearest-even; inputs are finite)
__device__ __forceinline__ unsigned int f2bf(float f) {
    unsigned int u = __float_as_uint(f);
    u += 0x7fffu + ((u >> 16) & 1u);
    return u >> 16;
}

// unpack 4 bf16 (as uint2) -> float4
__device__ __forceinline__ float4 bf4(uint2 v) {
    float4 f;
    f.x = __uint_as_float(v.x << 16);
    f.y = __uint_as_float(v.x & 0xffff0000u);
    f.z = __uint_as_float(v.y << 16);
    f.w = __uint_as_float(v.y & 0xffff0000u);
    return f;
}

// ---------------------------------------------------------------------------
// Transpose + cast: [N, C, S] f32 -> [N, S, C] bf16.
// Block handles 64 s x all 128 c. Channel PAIRS are packed to bf16x2 u32 in
// registers, so all LDS ops are 32-bit. u32 tile row stride 67:
// write banks (3*(s4+q) + cpair) % 32 -> exactly 2-way (free).
// ---------------------------------------------------------------------------
__global__ __launch_bounds__(256) void transpose_bf16(
    const float* __restrict__ in, unsigned int* __restrict__ outp) {
    __shared__ unsigned int tileu[64][67]; // [s][cpair] bf16x2
    const int n  = blockIdx.y;
    const int s0 = blockIdx.x * 64;
    const int t  = threadIdx.x;

    const float* src = in + (size_t)n * C_ * S_;
    // dst viewed as u32: [s][cpair], cpair = c/2
    unsigned int* dst = outp + (size_t)n * (C_ / 2) * S_;

    // Load phase: coalesced float4 along S for two adjacent channels; pack.
    {
        const int cp0 = t >> 4;       // 0..15
        const int s4  = (t & 15) * 4; // 0..60
#pragma unroll
        for (int p = 0; p < 4; ++p) {
            const int cp = cp0 + 16 * p;        // channel pair 0..63
            const int c = cp * 2;
            const float4 a = *(const float4*)&src[(size_t)c * S_ + (s0 + s4)];
            const float4 b =
                *(const float4*)&src[(size_t)(c + 1) * S_ + (s0 + s4)];
            tileu[s4 + 0][cp] = f2bf(a.x) | (f2bf(b.x) << 16);
            tileu[s4 + 1][cp] = f2bf(a.y) | (f2bf(b.y) << 16);
            tileu[s4 + 2][cp] = f2bf(a.z) | (f2bf(b.z) << 16);
            tileu[s4 + 3][cp] = f2bf(a.w) | (f2bf(b.w) << 16);
        }
    }
    __syncthreads();
    // Store phase: uint2 per lane -> 512 B contiguous per wave.
    {
        const int sl  = t >> 5;       // 0..7
        const int cp2 = (t & 31) * 2; // 0..62
#pragma unroll
        for (int p = 0; p < 8; ++p) {
            const int s = sl + 8 * p;
            uint2 v;
            v.x = tileu[s][cp2 + 0];
            v.y = tileu[s][cp2 + 1];
            *(uint2*)&dst[(size_t)(s0 + s) * (C_ / 2) + cp2] = v;
        }
    }
}

// ---------------------------------------------------------------------------
// Main kernel: one block of 512 threads per (roi, pd) slab.
// 16 slot-groups x 32 lanes; each lane accumulates 4 channels of a bin.
// 4 blocks/CU x 8 waves = full 32-wave occupancy to hide gather latency.
// Results staged in LDS, stored in final [R, C, 196] layout (nontemporal).
// XCD swizzle: all 4 slabs of an ROI share blockIdx%8 -> same XCD L2.
// ---------------------------------------------------------------------------
__global__ __launch_bounds__(512) void roi_align_slab(
    const unsigned short* __restrict__ ft, // [N, D, H, W, C] bf16
    const float* __restrict__ rois,        // [R, 7]
    float* __restrict__ out,               // [R, C, PD, PH, PW]
    int R) {
    __shared__ __align__(16) float tile[SLAB][132];

    int r, pd;
    if ((R & 7) == 0) {
        const int xcd = blockIdx.x & 7;
        const int q = blockIdx.x >> 3;
        pd = q & 3;
        r = ((q >> 2) << 3) + xcd;
    } else {
        r = blockIdx.x >> 2;
        pd = blockIdx.x & 3;
    }

    const int t = threadIdx.x;
    const int grp = t >> 5;       // slot group 0..15
    const int c4 = (t & 31) * 4;  // channel base

    const float* roi = rois + (size_t)r * 7;
    const int b = (int)roi[0];
    const float x1 = roi[1] * SCALE, y1 = roi[2] * SCALE, z1 = roi[3] * SCALE;
    const float x2 = roi[4] * SCALE, y2 = roi[5] * SCALE, z2 = roi[6] * SCALE;
    const float rd = fmaxf(z2 - z1, 1.0f);
    const float rh = fmaxf(y2 - y1, 1.0f);
    const float rw = fmaxf(x2 - x1, 1.0f);

    int zlo[2], zhi[2];
    float wz[2];
    bool vz[2];
    axis2(z1, rd, PD, pd, D_, zlo, zhi, wz, vz);

#pragma unroll 1
    for (int k = 0; k < 4; ++k) {
        const int slot = grp + 16 * k;
        if (slot < SLAB) {
            const int ph = slot / PW;
            const int pw = slot - ph * PW;

            int ylo[2], yhi[2], xlo[2], xhi[2];
            float wy[2], wx[2];
            bool vy[2], vx[2];
            axis2(y1, rh, PH, ph, H_, ylo, yhi, wy, vy);
            axis2(x1, rw, PW, pw, W_, xlo, xhi, wx, vx);

            float4 acc = make_float4(0.f, 0.f, 0.f, 0.f);
#pragma unroll
            for (int i = 0; i < 2; ++i) {
                if (!vz[i]) continue;
                const float wz1 = wz[i], wz0 = 1.0f - wz1;
#pragma unroll
                for (int j = 0; j < 2; ++j) {
                    if (!vy[j]) continue;
                    const float wy1 = wy[j], wy0 = 1.0f - wy1;
                    const size_t r00 =
                        (((size_t)b * D_ + zlo[i]) * H_ + ylo[j]) * W_;
                    const size_t r10 =
                        (((size_t)b * D_ + zhi[i]) * H_ + ylo[j]) * W_;
                    const size_t r01 =
                        (((size_t)b * D_ + zlo[i]) * H_ + yhi[j]) * W_;
                    const size_t r11 =
                        (((size_t)b * D_ + zhi[i]) * H_ + yhi[j]) * W_;
#pragma unroll
                    for (int kk = 0; kk < 2; ++kk) {
                        if (!vx[kk]) continue;
                        const float wx1 = wx[kk], wx0 = 1.0f - wx1;
                        const size_t xl = xlo[kk], xh = xhi[kk];
                        const float4 f000 =
                            bf4(*(const uint2*)&ft[(r00 + xl) * C_ + c4]);
                        const float4 f001 =
                            bf4(*(const uint2*)&ft[(r00 + xh) * C_ + c4]);
                        const float4 f010 =
                            bf4(*(const uint2*)&ft[(r01 + xl) * C_ + c4]);
                        const float4 f011 =
                            bf4(*(const uint2*)&ft[(r01 + xh) * C_ + c4]);
                        const float4 f100 =
                            bf4(*(const uint2*)&ft[(r10 + xl) * C_ + c4]);
                        const float4 f101 =
                            bf4(*(const uint2*)&ft[(r10 + xh) * C_ + c4]);
                        const float4 f110 =
                            bf4(*(const uint2*)&ft[(r11 + xl) * C_ + c4]);
                        const float4 f111 =
                            bf4(*(const uint2*)&ft[(r11 + xh) * C_ + c4]);
                        const float w000 = wz0 * wy0 * wx0,
                                    w001 = wz0 * wy0 * wx1;
                        const float w010 = wz0 * wy1 * wx0,
                                    w011 = wz0 * wy1 * wx1;
                        const float w100 = wz1 * wy0 * wx0,
                                    w101 = wz1 * wy0 * wx1;
                        const float w110 = wz1 * wy1 * wx0,
                                    w111 = wz1 * wy1 * wx1;
                        acc.x += w000 * f000.x + w001 * f001.x +
                                 w010 * f010.x + w011 * f011.x +
                                 w100 * f100.x + w101 * f101.x +
                                 w110 * f110.x + w111 * f111.x;
                        acc.y += w000 * f000.y + w001 * f001.y +
                                 w010 * f010.y + w011 * f011.y +
                                 w100 * f100.y + w101 * f101.y +
                                 w110 * f110.y + w111 * f111.y;
                        acc.z += w000 * f000.z + w001 * f001.z +
                                 w010 * f010.z + w011 * f011.z +
                                 w100 * f100.z + w101 * f101.z +
                                 w110 * f110.z + w111 * f111.z;
                        acc.w += w000 * f000.w + w001 * f001.w +
                                 w010 * f010.w + w011 * f011.w +
                                 w100 * f100.w + w101 * f101.w +
                                 w110 * f110.w + w111 * f111.w;
                    }
                }
            }
            const float s = 1.0f / (SR * SR * SR);
            acc.x *= s; acc.y *= s; acc.z *= s; acc.w *= s;
            *(float4*)&tile[slot][c4] = acc;
        }
    }

    __syncthreads();

    // Store the slab in final layout: out[r][c][pd*49 + o], contiguous o-runs.
    const size_t obase = (size_t)r * C_ * BINS_PER_ROI + (size_t)pd * SLAB;
#pragma unroll 1
    for (int idx = t; idx < C_ * SLAB; idx += 512) {
        const int c = idx / SLAB;
        const int o = idx - c * SLAB;
        __builtin_nontemporal_store(tile[o][c],
                                    &out[obase + (size_t)c * BINS_PER_ROI + o]);
    }
}

// ---------------------------------------------------------------------------
// Fallback: thread-per-output, native layout (tiny ws only).
// ---------------------------------------------------------------------------
__global__ void roi_align_direct(const float* __restrict__ feat,
                                 const float* __restrict__ rois,
                                 float* __restrict__ out, int total) {
    const int tid = blockIdx.x * blockDim.x + threadIdx.x;
    if (tid >= total) return;
    int t = tid;
    const int pw = t % PW; t /= PW;
    const int ph = t % PH; t /= PH;
    const int pd = t % PD; t /= PD;
    const int c = t % C_;  t /= C_;
    const int r = t;

    const float* roi = rois + (size_t)r * 7;
    const int b = (int)roi[0];
    const float x1 = roi[1] * SCALE, y1 = roi[2] * SCALE, z1 = roi[3] * SCALE;
    const float x2 = roi[4] * SCALE, y2 = roi[5] * SCALE, z2 = roi[6] * SCALE;
    const float rd = fmaxf(z2 - z1, 1.0f);
    const float rh = fmaxf(y2 - y1, 1.0f);
    const float rw = fmaxf(x2 - x1, 1.0f);

    int zlo[2], zhi[2], ylo[2], yhi[2], xlo[2], xhi[2];
    float wz[2], wy[2], wx[2];
    bool vz[2], vy[2], vx[2];
    axis2(z1, rd, PD, pd, D_, zlo, zhi, wz, vz);
    axis2(y1, rh, PH, ph, H_, ylo, yhi, wy, vy);
    axis2(x1, rw, PW, pw, W_, xlo, xhi, wx, vx);

    const float* fc = feat + ((size_t)b * C_ + c) * S_;
    float acc = 0.0f;
#pragma unroll
    for (int i = 0; i < 2; ++i) {
        if (!vz[i]) continue;
#pragma unroll
        for (int j = 0; j < 2; ++j) {
            if (!vy[j]) continue;
            const size_t r00 = ((size_t)zlo[i] * H_ + ylo[j]) * W_;
            const size_t r10 = ((size_t)zhi[i] * H_ + ylo[j]) * W_;
            const size_t r01 = ((size_t)zlo[i] * H_ + yhi[j]) * W_;
            const size_t r11 = ((size_t)zhi[i] * H_ + yhi[j]) * W_;
            const float wz1 = wz[i], wz0 = 1.0f - wz1;
            const float wy1 = wy[j], wy0 = 1.0f - wy1;
#pragma unroll
            for (int k = 0; k < 2; ++k) {
                if (!vx[k]) continue;
                const float wx1 = wx[k], wx0 = 1.0f - wx1;
                acc += wz0 * (wy0 * (wx0 * fc[r00 + xlo[k]] + wx1 * fc[r00 + xhi[k]]) +
                              wy1 * (wx0 * fc[r01 + xlo[k]] + wx1 * fc[r01 + xhi[k]])) +
                       wz1 * (wy0 * (wx0 * fc[r10 + xlo[k]] + wx1 * fc[r10 + xhi[k]]) +
                              wy1 * (wx0 * fc[r11 + xlo[k]] + wx1 * fc[r11 + xhi[k]]));
            }
        }
    }
    out[tid] = acc * (1.0f / (SR * SR * SR));
}

extern "C" void kernel_launch(void* const* d_in, const int* in_sizes, int n_in,
                              void* d_out, int out_size, void* d_ws,
                              size_t ws_size, hipStream_t stream) {
    const float* features = (const float*)d_in[0];
    const float* rois = (const float*)d_in[1];
    float* out = (float*)d_out;

    const int R = in_sizes[1] / 7;
    const int N = in_sizes[0] / (C_ * S_);
    const size_t need = (size_t)in_sizes[0] * sizeof(unsigned short);

    if (ws_size >= need) {
        unsigned short* ft = (unsigned short*)d_ws; // [N, D, H, W, C] bf16

        dim3 tg(S_ / 64, N);
        transpose_bf16<<<tg, 256, 0, stream>>>(features, (unsigned int*)ft);

        roi_align_slab<<<R * PD, 512, 0, stream>>>(ft, rois, out, R);
    } else {
        const int total = R * C_ * BINS_PER_ROI;
        roi_align_direct<<<(total + 255) / 256, 256, 0, stream>>>(
            features, rois, out, total);
    }
}